// Round 5
// baseline (237.025 us; speedup 1.0000x reference)
//
#include <hip/hip_runtime.h>

#define B_  8
#define C_  128
#define H_  96
#define W_  160
#define HWp (H_ * W_)   // 15360 floats per channel plane

typedef short  short8  __attribute__((ext_vector_type(8)));
typedef float  floatx4 __attribute__((ext_vector_type(4)));

// round-to-nearest-even fp32 -> bf16, packed pair (a low 16, b high 16)
__device__ __forceinline__ unsigned pk_bf16(float a, float b) {
    unsigned ua = __float_as_uint(a);
    unsigned ub = __float_as_uint(b);
    ua = (ua + 0x7FFFu + ((ua >> 16) & 1u)) >> 16;
    ub = (ub + 0x7FFFu + ((ub >> 16) & 1u)) & 0xFFFF0000u;
    return ua | ub;
}

// Band-GEMM correlation, DRAM-friendly decomposition:
//   out[b, dy*9+o, y, x] = (1/128) * sum_c one[b,c,y,x] * two[b,c,y+dy-4,x+o-4]
// Block = (b, y, x-half): y-tile 1, x-tile 80. Per c the 9 needed `two` rows are
// CONTIGUOUS memory (9 x 640 B); successive y-blocks slide by one row (L2 hits).
// LDS records: 16 B = 8 bf16 (k = q*8+j) at [qrow][nl], word = (qrow*S + nl)*4 + w.
// Odd strides (S=89 B / 81 A) give q-stride = 4 mod 32 -> conflict-free b128 reads.
// 70 MFMA tiles: T = mt*14+slot; slot<9: ct0 dy=slot; slot>=9: ct1 pp, dy=2pp+nh.
#define BWORDS 14240   // B region: qrow = ry*4+q (ry<10, row 9 = phantom junk) x 89 recs
#define AQ4    3560    // uint4 index of A region base (= BWORDS/4)

__global__ __launch_bounds__(1024, 4)
void corr_kernel(const float* __restrict__ one, const float* __restrict__ two,
                 float* __restrict__ out) {
    __shared__ unsigned sw[15536];          // 62,144 B; epilogue fp32 buffer aliases base
    uint4* s4 = reinterpret_cast<uint4*>(sw);
    float* ep = reinterpret_cast<float*>(sw);

    const int id = blockIdx.x;
    const int b  = id & 7;            // one batch per XCD
    const int jj = id >> 3;           // xh + 2*y : x-halves adjacent, y-sweep within XCD
    const int xh = jj & 1;
    const int y  = jj >> 1;
    const int x0 = xh * 80;

    const int tid  = threadIdx.x;
    const int lane = tid & 63;
    const int wv   = tid >> 6;
    const int q    = lane >> 4;
    const int n    = lane & 15;
    const int nh   = n >> 3;
    const int h    = n & 7;

    // ---- B staging tasks: t in [0,3168) = (ry9, cp16, xq22); x in LOW lane bits ----
    const float* bptr[4];
    int  bbase[4];
    bool bval[4];
    const bool bhas3 = (tid < 96);
    #pragma unroll
    for (int i = 0; i < 4; ++i) {
        int t = (i < 3) ? (tid + 1024 * i) : (3072 + (tid < 96 ? tid : 0));
        const int xq = t % 22;
        const int u  = t / 22;
        const int cp = u & 15;
        const int ry = u >> 4;                     // < 9
        const int ty  = y - 4 + ry;
        const int gxb = x0 - 4 + 4 * xq;
        const bool v  = ((unsigned)ty < H_) && (gxb >= 0) && (gxb <= W_ - 4);
        bval[i] = v;
        bptr[i] = two + ((size_t)(b * C_ + 2 * cp) * H_ + (v ? ty : 0)) * W_ + (v ? gxb : 0);
        bbase[i] = ((ry * 4 + (cp >> 2)) * 89 + 4 * xq) * 4 + (cp & 3);
    }

    // ---- A staging task: threads 704..1023 -> (cp16, xq20) ----
    const int  atr  = tid - 704;
    const bool ahas = (atr >= 0);
    const int  at   = ahas ? atr : 0;
    const int  acp  = at & 15;
    const int  axq  = at >> 4;                     // < 20
    const float* aptr = one + ((size_t)(b * C_ + 2 * acp) * H_ + y) * W_ + (x0 + 4 * axq);
    const int  abase  = BWORDS + ((acp >> 2) * 81 + 4 * axq) * 4 + (acp & 3);

    // ---- MFMA tile decode (wave w owns T = w + 16k, T < 70) ----
    int aidx[5], bidx[5], mts[5], slots[5];
    bool thas[5];
    #pragma unroll
    for (int k = 0; k < 5; ++k) {
        const int T = wv + 16 * k;
        thas[k] = (T < 70);
        const int Tc = thas[k] ? T : 0;
        const int mt = Tc / 14;
        const int sl = Tc % 14;
        mts[k] = mt; slots[k] = sl;
        aidx[k] = AQ4 + q * 81 + mt * 16 + n;
        bidx[k] = (sl < 9) ? (sl * 4 + q) * 89 + mt * 16 + n
                           : ((2 * (sl - 9) + nh) * 4 + q) * 89 + mt * 16 + 16 + h;
    }

    floatx4 acc[5];
    #pragma unroll
    for (int k = 0; k < 5; ++k) acc[k] = floatx4{0.f, 0.f, 0.f, 0.f};

    floatx4 bl[4][2], al[2];
    al[0] = floatx4{0.f,0.f,0.f,0.f}; al[1] = floatx4{0.f,0.f,0.f,0.f};
    auto issue = [&](int ck) {
        const size_t off = (size_t)ck * 32 * HWp;
        #pragma unroll
        for (int i = 0; i < 4; ++i) {
            const bool go = bval[i] && (i < 3 || bhas3);
            if (go) { bl[i][0] = *(const floatx4*)(bptr[i] + off);
                      bl[i][1] = *(const floatx4*)(bptr[i] + off + HWp); }
            else    { bl[i][0] = floatx4{0.f,0.f,0.f,0.f}; bl[i][1] = floatx4{0.f,0.f,0.f,0.f}; }
        }
        if (ahas) { al[0] = *(const floatx4*)(aptr + off);
                    al[1] = *(const floatx4*)(aptr + off + HWp); }
    };

    issue(0);

    #pragma unroll
    for (int ck = 0; ck < 4; ++ck) {
        // ---- commit prefetched raws -> LDS (zeros for padding tasks) ----
        #pragma unroll
        for (int i = 0; i < 4; ++i) {
            if (i < 3 || bhas3) {
                #pragma unroll
                for (int kk = 0; kk < 4; ++kk)
                    sw[bbase[i] + 4 * kk] = pk_bf16(bl[i][0][kk], bl[i][1][kk]);
            }
        }
        if (ahas) {
            #pragma unroll
            for (int kk = 0; kk < 4; ++kk)
                sw[abase + 4 * kk] = pk_bf16(al[0][kk], al[1][kk]);
        }
        __syncthreads();                       // staged chunk visible

        if (ck < 3) issue(ck + 1);             // next chunk lands during MFMA phase

        #pragma unroll
        for (int k = 0; k < 5; ++k) {
            if (thas[k]) {
                const short8 Af = *reinterpret_cast<const short8*>(&s4[aidx[k]]);
                const short8 Bf = *reinterpret_cast<const short8*>(&s4[bidx[k]]);
                acc[k] = __builtin_amdgcn_mfma_f32_16x16x32_bf16(Af, Bf, acc[k], 0, 0, 0);
            }
        }
        __syncthreads();                       // reads done; next commit may overwrite
    }

    // ---- epilogue: scatter accs -> ep (aliases B region), then coalesced stores ----
    const float scale = 1.0f / (float)C_;
    #pragma unroll
    for (int k = 0; k < 5; ++k) {
        if (thas[k]) {
            const int mt = mts[k], sl = slots[k];
            #pragma unroll
            for (int r = 0; r < 4; ++r) {
                const int m = 4 * q + r;
                if (sl < 9) {
                    const int o = n - m;
                    if ((unsigned)o <= 8u)
                        ep[(sl * 9 + o) * 81 + mt * 16 + m] = acc[k][r] * scale;
                } else {
                    const int dy = 2 * (sl - 9) + nh;     // dy=9 phantom discarded
                    const int o  = 16 + h - m;
                    if (dy <= 8 && (unsigned)o <= 8u)
                        ep[(dy * 9 + o) * 81 + mt * 16 + m] = acc[k][r] * scale;
                }
            }
        }
    }
    __syncthreads();
    #pragma unroll
    for (int i = 0; i < 7; ++i) {
        const int it = tid + 1024 * i;
        if (it < 6480) {
            const int ch = it / 80;
            const int xl = it - ch * 80;
            out[((size_t)(b * 81 + ch) * H_ + y) * W_ + (x0 + xl)] = ep[ch * 81 + xl];
        }
    }
}

extern "C" void kernel_launch(void* const* d_in, const int* in_sizes, int n_in,
                              void* d_out, int out_size, void* d_ws, size_t ws_size,
                              hipStream_t stream) {
    const float* one = (const float*)d_in[0];
    const float* two = (const float*)d_in[1];
    float* out = (float*)d_out;
    // grid: 8 batches * 96 y * 2 x-halves = 1536 blocks of 1024 threads
    corr_kernel<<<dim3(1536), dim3(1024), 0, stream>>>(one, two, out);
}